// Round 2
// baseline (132.136 us; speedup 1.0000x reference)
//
#include <hip/hip_runtime.h>

// Problem constants
#define NN 16        // batch
#define PB 16        // predicted masks
#define TB 8         // true masks
#define HWPX 50176   // 224*224
#define WORDS 784    // u64 words per plane (50176/64)
#define HALF 392     // words per half-plane
#define GROUPS 196   // 256-pixel groups per plane
#define TOTAL_GROUPS ((NN * PB + NN * TB) * GROUPS)  // 75264
#define K2_CH 16     // score-phase blocks per batch element
#define WPC (WORDS / K2_CH)  // 49 words per score chunk

// ---------------------------------------------------------------------------
// K1: bitpack both inputs (77 MB fp32 -> 2.4 MB bits) + zero d_out.
// Each wave-iteration: 64 lanes load float4 (1 KiB coalesced), 4 ballots
// produce 4 u64 words, lane 0 stores 32 B. The pixel->bit mapping is a fixed
// permutation identical for pred and true planes, so popcount intersections
// and the permutation-invariant final mean are unaffected.
// ---------------------------------------------------------------------------
__global__ __launch_bounds__(256) void pack_kernel(
        const float* __restrict__ pred, const float* __restrict__ truth,
        unsigned long long* __restrict__ PP, unsigned long long* __restrict__ PT,
        float* __restrict__ out) {
    if (blockIdx.x == 0 && threadIdx.x < NN) out[threadIdx.x] = 0.f;

    const int wavesPerBlock = blockDim.x >> 6;
    const int waveId = blockIdx.x * wavesPerBlock + (threadIdx.x >> 6);
    const int lane = threadIdx.x & 63;
    const int nWaves = gridDim.x * wavesPerBlock;

    for (int G = waveId; G < TOTAL_GROUPS; G += nWaves) {
        int plane = G / GROUPS;
        int g = G - plane * GROUPS;
        const float* src;
        unsigned long long* dst;
        if (plane < NN * PB) {
            src = pred + (size_t)plane * HWPX;
            dst = PP + (size_t)plane * WORDS;
        } else {
            int q = plane - NN * PB;
            src = truth + (size_t)q * HWPX;
            dst = PT + (size_t)q * WORDS;
        }
        const float4 v = *(const float4*)(src + g * 256 + lane * 4);
        unsigned long long b0 = __ballot(v.x != 0.0f);
        unsigned long long b1 = __ballot(v.y != 0.0f);
        unsigned long long b2 = __ballot(v.z != 0.0f);
        unsigned long long b3 = __ballot(v.w != 0.0f);
        if (lane == 0) {
            ulonglong2 lo, hi;
            lo.x = b0; lo.y = b1; hi.x = b2; hi.y = b3;
            ((ulonglong2*)dst)[g * 2 + 0] = lo;
            ((ulonglong2*)dst)[g * 2 + 1] = hi;
        }
    }
}

// ---------------------------------------------------------------------------
// K2 (fused): per block, recompute inters[n,:,:] / sp / st from packed bits
// (redundant x16 per n, but L2-resident and ~2 us), derive iou_maxs[n,:],
// then score a 49-word chunk of pixels. Division-free epilogue: denominator
// is an integer in [0,16] -> 17-entry LDS reciprocal table (entry 0 = 0
// implements the isfinite->0 rule).
// ---------------------------------------------------------------------------
__global__ __launch_bounds__(256) void fused_kernel(
        const unsigned long long* __restrict__ PP,
        const unsigned long long* __restrict__ PT,
        float* __restrict__ out) {
    const int n = blockIdx.x / K2_CH;
    const int c = blockIdx.x % K2_CH;
    const int tid = threadIdx.x;

    __shared__ int inters_s[PB * TB];
    __shared__ int sp_s[PB];
    __shared__ int st_s[TB];
    __shared__ float ioumax_s[PB];
    __shared__ float rcp_s[17];
    __shared__ float red_s[4];

    if (tid < 17) rcp_s[tid] = tid ? 1.0f / (float)tid : 0.0f;

    // ---- phase A: intersection/count popcounts (2 threads per (p,t) pair) ----
    const int pair = tid >> 1;       // 0..127
    const int h = tid & 1;           // word-half
    const int p = pair >> 3, t = pair & 7;
    const ulonglong2* pp2 =
        (const ulonglong2*)(PP + ((size_t)n * PB + p) * WORDS + h * HALF);
    const ulonglong2* pt2 =
        (const ulonglong2*)(PT + ((size_t)n * TB + t) * WORDS + h * HALF);
    int acc = 0, accp = 0, acct = 0;
#pragma unroll 4
    for (int i = 0; i < HALF / 2; ++i) {
        ulonglong2 a = pp2[i];
        ulonglong2 b = pt2[i];
        acc  += __popcll(a.x & b.x) + __popcll(a.y & b.y);
        accp += __popcll(a.x) + __popcll(a.y);
        acct += __popcll(b.x) + __popcll(b.y);
    }
    acc  += __shfl_xor(acc, 1, 64);   // partner h-half is the adjacent lane
    accp += __shfl_xor(accp, 1, 64);
    acct += __shfl_xor(acct, 1, 64);
    if (h == 0) {
        inters_s[pair] = acc;
        if (t == 0) sp_s[p] = accp;
        if (p == 0) st_s[t] = acct;
    }
    __syncthreads();

    // ---- phase B: iou_maxs[n,p] ----
    if (tid < PB) {
        float spv = (float)sp_s[tid];
        float m = 0.f;
#pragma unroll
        for (int tt = 0; tt < TB; ++tt) {
            float iv = (float)inters_s[tid * TB + tt];
            float un = spv + (float)st_s[tt] - iv;
            m = fmaxf(m, un > 0.f ? iv / un : 0.f);
        }
        ioumax_s[tid] = m;
    }
    __syncthreads();

    // ---- phase C: per-pixel weighted score over this block's 49-word chunk ----
    float iom[PB];
#pragma unroll
    for (int q = 0; q < PB; ++q) iom[q] = ioumax_s[q];

    const int lane = tid & 63;
    const int wv = tid >> 6;
    const unsigned long long* base = PP + (size_t)n * PB * WORDS;
    float sum = 0.f;
    for (int w = c * WPC + wv; w < (c + 1) * WPC; w += 4) {
        float num = 0.f;
        unsigned int den = 0;
#pragma unroll
        for (int q = 0; q < PB; ++q) {
            unsigned long long m = base[(size_t)q * WORDS + w];
            unsigned int bit = (unsigned int)(m >> lane) & 1u;
            den += bit;
            num = fmaf((float)bit, iom[q], num);
        }
        sum += num * rcp_s[den];
    }

    // ---- block reduction + one atomic per block ----
#pragma unroll
    for (int off = 32; off > 0; off >>= 1) sum += __shfl_down(sum, off, 64);
    if (lane == 0) red_s[wv] = sum;
    __syncthreads();
    if (tid == 0) {
        atomicAdd(&out[n],
                  (red_s[0] + red_s[1] + red_s[2] + red_s[3]) * (1.0f / (float)HWPX));
    }
}

// ---------------------------------------------------------------------------
extern "C" void kernel_launch(void* const* d_in, const int* in_sizes, int n_in,
                              void* d_out, int out_size, void* d_ws, size_t ws_size,
                              hipStream_t stream) {
    const float* pred  = (const float*)d_in[0];   // (N,P,H,W) fp32 {0,1}
    const float* truth = (const float*)d_in[1];   // (N,T,H,W) fp32 {0,1}
    float* out = (float*)d_out;                   // (N,)

    unsigned long long* PP = (unsigned long long*)d_ws;      // 200704 u64
    unsigned long long* PT = PP + (size_t)NN * PB * WORDS;   // 100352 u64

    pack_kernel<<<2048, 256, 0, stream>>>(pred, truth, PP, PT, out);
    fused_kernel<<<NN * K2_CH, 256, 0, stream>>>(PP, PT, out);
}